// Round 5
// baseline (227.876 us; speedup 1.0000x reference)
//
#include <hip/hip_runtime.h>
#include <hip/hip_bf16.h>
#include <math.h>

#define BB 4
#define CC 64
#define HH 128
#define WW 128
#define HW (HH*WW)          // 16384
#define NPIX (BB*HW)        // 65536

typedef __attribute__((ext_vector_type(8))) short short8;   // 8 bf16
typedef __attribute__((ext_vector_type(4))) float f32x4;

__device__ __forceinline__ float bf2f(ushort u) {
  union { unsigned u; float f; } v; v.u = ((unsigned)u) << 16; return v.f;
}
__device__ __forceinline__ ushort f2bf(float f) {
  __hip_bfloat16 h = __float2bfloat16(f); return *(ushort*)&h;
}

// ---------------------------------------------------------------------------
// Prep (unchanged, verified): NCHW fp32 -> channels-last bf16 + weights.
// ---------------------------------------------------------------------------
__global__ __launch_bounds__(256) void k_prep(
    const float* __restrict__ x, const float* __restrict__ inter,
    const float* __restrict__ w_off, const float* __restrict__ w_dcn,
    const float* __restrict__ wg1, const float* __restrict__ wb1,
    const float* __restrict__ wg2, const float* __restrict__ wb2,
    ushort* __restrict__ x_clh, ushort* __restrict__ inter_clh,
    ushort* __restrict__ wfb, ushort* __restrict__ wdT,
    ushort* __restrict__ w1gb, ushort* __restrict__ w1bb,
    ushort* __restrict__ w2gb, ushort* __restrict__ w2bb,
    float* __restrict__ zp) {
  __shared__ __align__(16) float tile[64 * 128];   // 32 KiB, xor-swizzled
  int blk = blockIdx.x;
  int tid = threadIdx.x;
  if (blk < 1024) {
    int sel = blk >> 9;
    int bh = blk & 511;
    int b = bh >> 7, h = bh & 127;
    const float* src = sel ? inter : x;
    ushort* dst = sel ? inter_clh : x_clh;
    const float* sp = src + (size_t)(b * 64) * HW + h * WW;
#pragma unroll
    for (int it = 0; it < 8; ++it) {
      int idx = it * 256 + tid;
      int c = idx >> 5, wq = idx & 31;
      float4 v = *(const float4*)(sp + (size_t)c * HW + wq * 4);
      int s = (c >> 3) & 7;
      *(float4*)(&tile[c * 128 + ((wq ^ s) << 2)]) = v;
    }
    __syncthreads();
    ushort* dp = dst + ((size_t)b * HW + h * WW) * 64;
#pragma unroll
    for (int it = 0; it < 4; ++it) {
      int idx = it * 256 + tid;
      int w = idx >> 3, c8 = idx & 7;
      short8 outv;
#pragma unroll
      for (int j = 0; j < 8; ++j) {
        int c = c8 * 8 + j;
        int sl = (w >> 2) ^ c8;
        float f = tile[c * 128 + (sl << 2) + (w & 3)];
        outv[j] = (short)f2bf(f);
      }
      *(short8*)(dp + (size_t)w * 64 + c8 * 8) = outv;
    }
  } else if (blk < 1168) {
    int i = (blk - 1024) * 256 + tid;
    if (i < 64) zp[i] = 0.f;
    if (i < 9 * 32 * 128) {
      int tap = i >> 12, rem = i & 4095, m = rem >> 7, c = rem & 127;
      float v = (m < 27) ? w_off[(size_t)(m * 128 + c) * 9 + tap] : 0.f;
      wfb[i] = f2bf(v);
    }
  } else if (blk < 1312) {
    int i = (blk - 1168) * 256 + tid;
    if (i < 64 * 64 * 9) {
      int o = i / 576, rem = i % 576, k = rem >> 6, c = rem & 63;
      wdT[i] = f2bf(w_dcn[(o * 64 + c) * 9 + k]);
    }
  } else {
    int i = (blk - 1312) * 256 + tid;   // 0..16383
    int m = i >> 12, j = i & 4095;
    const float* src = (m == 0) ? wg1 : (m == 1) ? wb1 : (m == 2) ? wg2 : wb2;
    ushort* dst = (m == 0) ? w1gb : (m == 1) ? w1bb : (m == 2) ? w2gb : w2bb;
    dst[j] = f2bf(src[j]);
  }
}

// ---------------------------------------------------------------------------
// OMEGA v5: wave-private pixel groups, barrier-free register-resident DCN.
//  Block = 256 thr (4 waves) = 64 px; grid 1024 = exactly 4 blocks/CU, all
//  co-resident in ONE round. Wave w owns pixels [w*16, w*16+16) (= MFMA cols)
//  and computes ALL 64 output channels for them.
//  - conv: B-frags direct from global (v4-verified pattern incl. quad*8),
//    2 m-groups/wave -> om rows in regs -> oml LDS.
//  - SFT: stage A (4 og) -> Sg/Sb (pitch 72) -> stage B -> ev[4][4] in regs.
//  - DCN: B-frag k-slice (tap t, ch h2*32+quad*8) at col px IS the lane's own
//    bilinear gather -> built in registers -> MFMA directly. NO S buffer,
//    NO barriers in the whole DCN loop (was 6 barriers + LDS round-trip).
//  - 3 __syncthreads total.
// LDS (25560 B -> 6/CU by LDS; 4/CU by VGPR cap 128):
//   shorts [0,4608)     Sg 64px x 72     | bytes [0,6912): cycx/cwy/cwx alias
//   shorts [4608,9216)  Sb 64px x 72     |   (written after B2, Sg/Sb dead)
//   shorts [9216,12780) oml f32 27 x 66  (rows 18-26 become sigmoid(m))
// ---------------------------------------------------------------------------
#define NPX 64
#define SGP 72       // Sg/Sb short pitch per pixel
#define OMP 66       // oml f32 pitch per m-row

__global__ __launch_bounds__(256, 4) void k_omega(
    const float* __restrict__ x, const ushort* __restrict__ x_clh,
    const ushort* __restrict__ inter_clh,
    const float* __restrict__ b_off, const ushort* __restrict__ wfb,
    const ushort* __restrict__ wdT,
    const ushort* __restrict__ w1gb, const ushort* __restrict__ w1bb,
    const ushort* __restrict__ w2gb, const ushort* __restrict__ w2bb,
    const ushort* __restrict__ zp16, float* __restrict__ out) {
  __shared__ __align__(16) ushort LDSB[12780];          // 25560 B
  ushort* Sg = LDSB;                                     // phases A-B
  ushort* Sb = LDSB + 4608;
  int*   cycx = (int*)LDSB;                              // 576 (after B2)
  float* cwy  = (float*)(LDSB + 1152);                   // 576
  float* cwx  = (float*)(LDSB + 2304);                   // 576
  float* oml  = (float*)(LDSB + 9216);                   // 27 x 66 f32

  int tid = threadIdx.x;
  int wave = tid >> 6, lane = tid & 63;
  int quad = lane >> 4, col = lane & 15;
  // XCD-local swizzle (1024 % 8 == 0 -> bijective).
  int bid = blockIdx.x;
  int wid = (bid & 7) * 128 + (bid >> 3);
  int pg0 = wid * NPX;
  int b = pg0 >> 14, hw0 = pg0 & 16383;
  int h = hw0 >> 7, w0 = hw0 & 127;        // w0 in {0, 64}
  int pxl = wave * 16 + col;               // wave-private pixel, local 0..63
  int pxg = pg0 + pxl;                     // global pixel index

  // ---- phase 1: conv MFMAs (B direct from global), 2 m-groups ----
  f32x4 am0 = {0.f, 0.f, 0.f, 0.f}, am1 = {0.f, 0.f, 0.f, 0.f};
  {
    const ushort* wb0 = wfb + (size_t)col * 128 + quad * 8;          // m 0-15
    const ushort* wb1 = wfb + (size_t)(16 + col) * 128 + quad * 8;   // m 16-31
    unsigned bbase = (unsigned)b * HW;
#pragma unroll
    for (int ky = 0; ky < 3; ++ky) {
      int hs = h + ky - 1;
      bool oky = (unsigned)hs < 128u;
      int rowb = hs << 7;
#pragma unroll
      for (int kx = 0; kx < 3; ++kx) {
        int ws = w0 + pxl + kx - 1;
        bool ok = oky && ((unsigned)ws < 128u);
        long long poff = (long long)(int)(bbase + rowb + ws) * 64;
        const ushort* bx = (ok ? x_clh + poff : zp16) + quad * 8;
        const ushort* bi = (ok ? inter_clh + poff : zp16) + quad * 8;
        int tap = ky * 3 + kx;
        const ushort* wt0 = wb0 + (size_t)tap * 4096;
        const ushort* wt1 = wb1 + (size_t)tap * 4096;
#pragma unroll
        for (int ks = 0; ks < 2; ++ks) {
          short8 b0 = *(const short8*)(bx + ks * 32);
          short8 b1 = *(const short8*)(bi + ks * 32);
          am0 = __builtin_amdgcn_mfma_f32_16x16x32_bf16(*(const short8*)(wt0 + ks * 32), b0, am0, 0, 0, 0);
          am0 = __builtin_amdgcn_mfma_f32_16x16x32_bf16(*(const short8*)(wt0 + 64 + ks * 32), b1, am0, 0, 0, 0);
          am1 = __builtin_amdgcn_mfma_f32_16x16x32_bf16(*(const short8*)(wt1 + ks * 32), b0, am1, 0, 0, 0);
          am1 = __builtin_amdgcn_mfma_f32_16x16x32_bf16(*(const short8*)(wt1 + 64 + ks * 32), b1, am1, 0, 0, 0);
        }
      }
    }
  }
  // om -> oml LDS (rows m, cols px-local)
#pragma unroll
  for (int r = 0; r < 4; ++r) {
    int m0 = quad * 4 + r;
    oml[m0 * OMP + pxl] = am0[r];
    int m1 = 16 + quad * 4 + r;
    if (m1 < 27) oml[m1 * OMP + pxl] = am1[r];
  }

  // ---- phase 2: SFT stage A (all 64 o for my 16 px) -> Sg/Sb ----
  f32x4 ag[4], ab[4];
#pragma unroll
  for (int og = 0; og < 4; ++og) {
    ag[og] = (f32x4){0.f, 0.f, 0.f, 0.f};
    ab[og] = (f32x4){0.f, 0.f, 0.f, 0.f};
  }
#pragma unroll
  for (int ks = 0; ks < 2; ++ks) {
    short8 bf = *(const short8*)(inter_clh + (size_t)pxg * 64 + ks * 32 + quad * 8);
#pragma unroll
    for (int og = 0; og < 4; ++og) {
      short8 a_g = *(const short8*)(w1gb + (size_t)(og * 16 + col) * 64 + ks * 32 + quad * 8);
      short8 a_b = *(const short8*)(w1bb + (size_t)(og * 16 + col) * 64 + ks * 32 + quad * 8);
      ag[og] = __builtin_amdgcn_mfma_f32_16x16x32_bf16(a_g, bf, ag[og], 0, 0, 0);
      ab[og] = __builtin_amdgcn_mfma_f32_16x16x32_bf16(a_b, bf, ab[og], 0, 0, 0);
    }
  }
#pragma unroll
  for (int og = 0; og < 4; ++og) {
    ushort pkg[4], pkb[4];
#pragma unroll
    for (int r = 0; r < 4; ++r) {
      float vg = ag[og][r]; vg = vg >= 0.f ? vg : 0.1f * vg;
      float vb = ab[og][r]; vb = vb >= 0.f ? vb : 0.1f * vb;
      pkg[r] = f2bf(vg); pkb[r] = f2bf(vb);
    }
    *(uint2*)(&Sg[pxl * SGP + og * 16 + quad * 4]) = *(uint2*)pkg;
    *(uint2*)(&Sb[pxl * SGP + og * 16 + quad * 4]) = *(uint2*)pkb;
  }
  __syncthreads();   // B1: oml + Sg/Sb visible

  // ---- phase 3: SFT stage B -> ev[4][4] (x + x*gamma + beta) ----
  f32x4 gg[4], gb[4];
#pragma unroll
  for (int og = 0; og < 4; ++og) {
    gg[og] = (f32x4){0.f, 0.f, 0.f, 0.f};
    gb[og] = (f32x4){0.f, 0.f, 0.f, 0.f};
  }
#pragma unroll
  for (int ks = 0; ks < 2; ++ks) {
    short8 bgf = *(const short8*)(Sg + pxl * SGP + ks * 32 + quad * 8);
    short8 bbf = *(const short8*)(Sb + pxl * SGP + ks * 32 + quad * 8);
#pragma unroll
    for (int og = 0; og < 4; ++og) {
      short8 a_g = *(const short8*)(w2gb + (size_t)(og * 16 + col) * 64 + ks * 32 + quad * 8);
      short8 a_b = *(const short8*)(w2bb + (size_t)(og * 16 + col) * 64 + ks * 32 + quad * 8);
      gg[og] = __builtin_amdgcn_mfma_f32_16x16x32_bf16(a_g, bgf, gg[og], 0, 0, 0);
      gb[og] = __builtin_amdgcn_mfma_f32_16x16x32_bf16(a_b, bbf, gb[og], 0, 0, 0);
    }
  }
  float ev[4][4];
#pragma unroll
  for (int og = 0; og < 4; ++og)
#pragma unroll
    for (int r = 0; r < 4; ++r) {
      int o = og * 16 + quad * 4 + r;
      float xv = x[(size_t)(b * 64 + o) * HW + hw0 + pxl];
      ev[og][r] = xv + xv * gg[og][r] + gb[og][r];
    }
  __syncthreads();   // B2: Sg/Sb dead -> region becomes coords

  // ---- phase 4: coords (9 taps x 64 px) + sigmoid(m) in-place ----
  for (int i = tid; i < 9 * NPX; i += 256) {
    int t = i >> 6, p = i & 63;
    float dy = oml[t * OMP + p] + b_off[t];
    float dx = oml[(9 + t) * OMP + p] + b_off[9 + t];
    float mz = oml[(18 + t) * OMP + p] + b_off[18 + t];
    float py = (float)(h + (t / 3) - 1) + dy;
    float px = (float)(w0 + p + (t % 3) - 1) + dx;
    float y0f = floorf(py), x0f = floorf(px);
    int iy = (int)y0f, ix = (int)x0f;
    cycx[i] = (iy & 0xffff) | (ix << 16);
    cwy[i] = py - y0f;
    cwx[i] = px - x0f;
    oml[(18 + t) * OMP + p] = 1.f / (1.f + __expf(-mz));
  }
  __syncthreads();   // B3: coords ready. No more barriers.

  // ---- phase 5: DCN — register-resident gather -> MFMA, barrier-free ----
  f32x4 acc[4];
#pragma unroll
  for (int og = 0; og < 4; ++og) acc[og] = (f32x4){0.f, 0.f, 0.f, 0.f};

  const ushort* bp = x_clh + (size_t)b * HW * 64 + quad * 8;
#pragma unroll 1
  for (int t = 0; t < 9; ++t) {
    int idx = t * 64 + pxl;
    int v = cycx[idx];
    int y0 = (int)(short)(v & 0xffff);
    int x0 = v >> 16;
    float wy = cwy[idx], wxx = cwx[idx];
    float m = oml[(18 + t) * OMP + pxl];
    bool yok0 = (unsigned)y0 < 128u, yok1 = (unsigned)(y0 + 1) < 128u;
    bool xok0 = (unsigned)x0 < 128u, xok1 = (unsigned)(x0 + 1) < 128u;
    const ushort* r0 = bp + (long long)(int)((y0 << 7) + x0) * 64;
    const ushort* r1 = r0 + (size_t)WW * 64;
#pragma unroll
    for (int h2 = 0; h2 < 2; ++h2) {
      int off = h2 * 32;
      short8 s00 = *(const short8*)((yok0 && xok0) ? (r0 + off) : (zp16 + off));
      short8 s01 = *(const short8*)((yok0 && xok1) ? (r0 + 64 + off) : (zp16 + off));
      short8 s10 = *(const short8*)((yok1 && xok0) ? (r1 + off) : (zp16 + off));
      short8 s11 = *(const short8*)((yok1 && xok1) ? (r1 + 64 + off) : (zp16 + off));
      short8 bfr;
#pragma unroll
      for (int j = 0; j < 8; ++j) {
        float v00 = bf2f((ushort)s00[j]), v01 = bf2f((ushort)s01[j]);
        float v10 = bf2f((ushort)s10[j]), v11 = bf2f((ushort)s11[j]);
        float top = v00 + (v01 - v00) * wxx;
        float bot = v10 + (v11 - v10) * wxx;
        float val = top + (bot - top) * wy;
        bfr[j] = (short)f2bf(val * m);
      }
#pragma unroll
      for (int og = 0; og < 4; ++og) {
        short8 a = *(const short8*)(wdT + (size_t)(og * 16 + col) * 576 + t * 64 + off + quad * 8);
        acc[og] = __builtin_amdgcn_mfma_f32_16x16x32_bf16(a, bfr, acc[og], 0, 0, 0);
      }
    }
  }

  // ---- phase 6: epilogue: out = ev + dcn (single pure write) ----
#pragma unroll
  for (int og = 0; og < 4; ++og)
#pragma unroll
    for (int r = 0; r < 4; ++r) {
      int o = og * 16 + quad * 4 + r;
      size_t idx = (size_t)(b * 64 + o) * HW + hw0 + pxl;
      out[idx] = ev[og][r] + acc[og][r];
    }
}

// ---------------------------------------------------------------------------
// Workspace plan (float slots), ~17 MB:
//   x_clh     ushort [0        .. 2097152)
//   inter_clh ushort [2097152  .. 4194304)
//   wfb       ushort [4194304  .. 4212736)
//   wdT       ushort [4212736  .. 4231168)
//   w1gb/w1bb/w2gb/w2bb ushort 4 x 2048 float slots [4231168 .. 4239360)
//   zp        fp32   [4239360  .. 4239424)
// ---------------------------------------------------------------------------
extern "C" void kernel_launch(void* const* d_in, const int* in_sizes, int n_in,
                              void* d_out, int out_size, void* d_ws, size_t ws_size,
                              hipStream_t stream) {
  const float* x     = (const float*)d_in[0];
  const float* inter = (const float*)d_in[1];
  const float* w_off = (const float*)d_in[2];
  const float* b_off = (const float*)d_in[3];
  const float* w_dcn = (const float*)d_in[4];
  const float* wg1   = (const float*)d_in[5];
  const float* wg2   = (const float*)d_in[6];
  const float* wb1   = (const float*)d_in[7];
  const float* wb2   = (const float*)d_in[8];
  float* out = (float*)d_out;

  float* ws        = (float*)d_ws;
  ushort* x_clh    = (ushort*)ws;
  ushort* inter_clh= (ushort*)(ws + 2097152);
  ushort* wfb      = (ushort*)(ws + 4194304);
  ushort* wdT      = (ushort*)(ws + 4212736);
  ushort* w1gb     = (ushort*)(ws + 4231168);
  ushort* w1bb     = (ushort*)(ws + 4233216);
  ushort* w2gb     = (ushort*)(ws + 4235264);
  ushort* w2bb     = (ushort*)(ws + 4237312);
  float* zp        = ws + 4239360;

  // Prep: channels-last bf16 inputs + all packed weights + zero page.
  k_prep<<<1376, 256, 0, stream>>>(x, inter, w_off, w_dcn, wg1, wb1, wg2, wb2,
                                   x_clh, inter_clh, wfb, wdT,
                                   w1gb, w1bb, w2gb, w2bb, zp);

  // Fully fused conv + SFT + DCN (v5: 64 px/block, barrier-free DCN).
  k_omega<<<1024, 256, 0, stream>>>(x, x_clh, inter_clh, b_off, wfb, wdT,
                                    w1gb, w1bb, w2gb, w2bb,
                                    (const ushort*)zp, out);
}

// Round 6
// 174.204 us; speedup vs baseline: 1.3081x; 1.3081x over previous
//
#include <hip/hip_runtime.h>
#include <hip/hip_bf16.h>
#include <math.h>

#define BB 4
#define CC 64
#define HH 128
#define WW 128
#define HW (HH*WW)          // 16384
#define NPIX (BB*HW)        // 65536

typedef __attribute__((ext_vector_type(8))) short short8;   // 8 bf16
typedef __attribute__((ext_vector_type(4))) float f32x4;

__device__ __forceinline__ float bf2f(ushort u) {
  union { unsigned u; float f; } v; v.u = ((unsigned)u) << 16; return v.f;
}
__device__ __forceinline__ ushort f2bf(float f) {
  __hip_bfloat16 h = __float2bfloat16(f); return *(ushort*)&h;
}

// ---------------------------------------------------------------------------
// Prep (round-1 verified): NCHW fp32 -> channels-last bf16 + weights.
// ---------------------------------------------------------------------------
__global__ __launch_bounds__(256) void k_prep(
    const float* __restrict__ x, const float* __restrict__ inter,
    const float* __restrict__ w_off, const float* __restrict__ w_dcn,
    const float* __restrict__ wg1, const float* __restrict__ wb1,
    const float* __restrict__ wg2, const float* __restrict__ wb2,
    ushort* __restrict__ x_clh, ushort* __restrict__ inter_clh,
    ushort* __restrict__ wfb, ushort* __restrict__ wdT,
    ushort* __restrict__ w1gb, ushort* __restrict__ w1bb,
    ushort* __restrict__ w2gb, ushort* __restrict__ w2bb,
    float* __restrict__ zp) {
  __shared__ __align__(16) float tile[64 * 128];   // 32 KiB, xor-swizzled
  int blk = blockIdx.x;
  int tid = threadIdx.x;
  if (blk < 1024) {
    int sel = blk >> 9;
    int bh = blk & 511;
    int b = bh >> 7, h = bh & 127;
    const float* src = sel ? inter : x;
    ushort* dst = sel ? inter_clh : x_clh;
    const float* sp = src + (size_t)(b * 64) * HW + h * WW;
#pragma unroll
    for (int it = 0; it < 8; ++it) {
      int idx = it * 256 + tid;
      int c = idx >> 5, wq = idx & 31;
      float4 v = *(const float4*)(sp + (size_t)c * HW + wq * 4);
      int s = (c >> 3) & 7;
      *(float4*)(&tile[c * 128 + ((wq ^ s) << 2)]) = v;
    }
    __syncthreads();
    ushort* dp = dst + ((size_t)b * HW + h * WW) * 64;
#pragma unroll
    for (int it = 0; it < 4; ++it) {
      int idx = it * 256 + tid;
      int w = idx >> 3, c8 = idx & 7;
      short8 outv;
#pragma unroll
      for (int j = 0; j < 8; ++j) {
        int c = c8 * 8 + j;
        int sl = (w >> 2) ^ c8;
        float f = tile[c * 128 + (sl << 2) + (w & 3)];
        outv[j] = (short)f2bf(f);
      }
      *(short8*)(dp + (size_t)w * 64 + c8 * 8) = outv;
    }
  } else if (blk < 1168) {
    int i = (blk - 1024) * 256 + tid;
    if (i < 64) zp[i] = 0.f;
    if (i < 9 * 32 * 128) {
      int tap = i >> 12, rem = i & 4095, m = rem >> 7, c = rem & 127;
      float v = (m < 27) ? w_off[(size_t)(m * 128 + c) * 9 + tap] : 0.f;
      wfb[i] = f2bf(v);
    }
  } else if (blk < 1312) {
    int i = (blk - 1168) * 256 + tid;
    if (i < 64 * 64 * 9) {
      int o = i / 576, rem = i % 576, k = rem >> 6, c = rem & 63;
      wdT[i] = f2bf(w_dcn[(o * 64 + c) * 9 + k]);
    }
  } else {
    int i = (blk - 1312) * 256 + tid;   // 0..16383
    int m = i >> 12, j = i & 4095;
    const float* src = (m == 0) ? wg1 : (m == 1) ? wb1 : (m == 2) ? wg2 : wb2;
    ushort* dst = (m == 0) ? w1gb : (m == 1) ? w1bb : (m == 2) ? w2gb : w2bb;
    dst[j] = f2bf(src[j]);
  }
}

// ---------------------------------------------------------------------------
// OMEGA v6 = round-1 kernel (session best, 83 us) + two bounded edits:
//  (a) ev-folding: gamma/beta/x collapsed to ev[2][4] right after phase 4
//      (v4-verified), freeing 16 VGPRs across phases 5-6.
//  (b) phase-6 software pipeline: one-chunk corner register bank; chunk k+1's
//      12 gather loads are ISSUED before the S-ready barrier of chunk k, so
//      their L2/L3 latency hides under barrier+MFMA+barrier. Prologue load
//      for chunk 0 stays exposed. Barrier count unchanged (8 total).
//  Everything else byte-identical to round-1. NO launch_bounds clamp
//  (both spill disasters came from clamps; tripwire = WRITE_SIZE > 16384 KB).
// LDS alias map (bytes in BIGB, 29376 B):
//   [0,29376)      phase 1-2: conv halo (204 rows x 72 shorts)
//   [0,12800)      phase 6:   S gather buffer (32 px x 200 shorts)
//   [12800,22016)  phase 3-4: Sg/Sb (2 x 32 x 72 shorts)
//   [12800,18560)  phase 5-6: coords (5 x 288 x 4 B)
//   [22016,25712)  phase 3-6: om_local (27 x 33 f32, written after halo dies)
// ---------------------------------------------------------------------------
#define CPITCH 72    // shorts per (srcrow, px) channel row in conv halo
#define SPITCH 200   // shorts per pixel row in gather buffer S
#define NPX 32       // pixels per block
#define FPX 72       // shorts per px row in Sg/Sb

__global__ __launch_bounds__(256) void k_omega(
    const float* __restrict__ x, const ushort* __restrict__ x_clh,
    const ushort* __restrict__ inter_clh,
    const float* __restrict__ b_off, const ushort* __restrict__ wfb,
    const ushort* __restrict__ wdT,
    const ushort* __restrict__ w1gb, const ushort* __restrict__ w1bb,
    const ushort* __restrict__ w2gb, const ushort* __restrict__ w2bb,
    const ushort* __restrict__ zp16, float* __restrict__ out) {
  __shared__ __align__(16) ushort BIGB[6 * 34 * CPITCH];   // 29376 B total LDS
  ushort* S  = BIGB;                      // 32*200 shorts = 12800 B (phases 1,6)
  ushort* Sg = BIGB + 6400;               // 32*72 shorts (phases 3-4)
  ushort* Sb = Sg + NPX * FPX;            // ends at short 11008 = byte 22016
  int*   cy  = (int*)(BIGB + 6400);       // coords (phases 5-6): 288 each
  int*   cx  = cy + 288;
  float* cwy = (float*)(cx + 288);
  float* cwx = cwy + 288;
  float* cm  = cwx + 288;                 // 5760 B total, ends byte 18560
  float* oml = (float*)(BIGB + 11008);    // om_local 27x33 f32 @ byte 22016

  int tid = threadIdx.x;
  int wave = tid >> 6, lane = tid & 63;
  int quad = lane >> 4, col = lane & 15;
  int rr = lane >> 3, g = lane & 7;
  int pg0 = blockIdx.x * NPX;
  int b = pg0 >> 14, hw0 = pg0 & 16383;
  int h = hw0 >> 7, w0 = hw0 & 127;
  int pt = wave >> 1, mt = wave & 1;
  int o_base = __builtin_amdgcn_readfirstlane(wave * 16);

  // ---- phase 1: conv halo staging ----
  {
    int ch = (tid & 7) * 8;
    unsigned bbase = (unsigned)b * HW;
#pragma unroll
    for (int it = 0; it < 7; ++it) {
      int e = it * 32 + (tid >> 3);
      if (e < 204) {
        int srcrow = e / 34, pxl = e % 34;
        int src = srcrow / 3, row = srcrow % 3;
        int hs = h + row - 1;
        int ps = w0 + pxl - 1;
        bool ok = ((unsigned)hs < 128u) && ((unsigned)ps < 128u);
        int hc = hs < 0 ? 0 : (hs > 127 ? 127 : hs);
        int pc = ps < 0 ? 0 : (ps > 127 ? 127 : ps);
        const ushort* sb = src ? inter_clh : x_clh;
        short8 v = *(const short8*)(sb + ((size_t)(bbase + (hc << 7) + pc)) * 64 + ch);
        short8 z = {0, 0, 0, 0, 0, 0, 0, 0};
        if (!ok) v = z;
        *(short8*)(&BIGB[e * CPITCH + ch]) = v;
      }
    }
  }
  __syncthreads();

  // ---- phase 2: conv MFMAs -> registers (oml store deferred past barrier) ----
  f32x4 accx = {0.f, 0.f, 0.f, 0.f}, acci = {0.f, 0.f, 0.f, 0.f};
  {
    const ushort* wb0 = wfb + (size_t)(mt * 16 + col) * 128 + quad * 8;
    int pxb = pt * 16 + col;
#pragma unroll
    for (int ky = 0; ky < 3; ++ky) {
#pragma unroll
      for (int kx = 0; kx < 3; ++kx) {
        int tap = ky * 3 + kx;
        const ushort* wt = wb0 + (size_t)tap * 4096;
#pragma unroll
        for (int ks = 0; ks < 2; ++ks) {
          short8 a0 = *(const short8*)(wt + ks * 32);
          short8 b0 = *(const short8*)(&BIGB[(ky * 34 + pxb + kx) * CPITCH + ks * 32 + quad * 8]);
          accx = __builtin_amdgcn_mfma_f32_16x16x32_bf16(a0, b0, accx, 0, 0, 0);
          short8 a1 = *(const short8*)(wt + 64 + ks * 32);
          short8 b1 = *(const short8*)(&BIGB[((3 + ky) * 34 + pxb + kx) * CPITCH + ks * 32 + quad * 8]);
          acci = __builtin_amdgcn_mfma_f32_16x16x32_bf16(a1, b1, acci, 0, 0, 0);
        }
      }
    }
  }
  __syncthreads();   // all waves done READING halo; BIGB free for aliases

  // oml store into BIGB tail (disjoint from Sg/Sb written in phase 3).
#pragma unroll
  for (int r = 0; r < 4; ++r) {
    int o = mt * 16 + quad * 4 + r;
    if (o < 27) oml[o * 33 + pt * 16 + col] = accx[r] + acci[r];
  }

  // ---- phase 3: SFT stage A -> Sg/Sb ----
  f32x4 ag[2], ab[2];
#pragma unroll
  for (int nt = 0; nt < 2; ++nt) {
    ag[nt] = (f32x4){0.f, 0.f, 0.f, 0.f};
    ab[nt] = (f32x4){0.f, 0.f, 0.f, 0.f};
  }
#pragma unroll
  for (int ks = 0; ks < 2; ++ks) {
    short8 a_g = *(const short8*)(w1gb + (size_t)(o_base + col) * 64 + ks * 32 + quad * 8);
    short8 a_b = *(const short8*)(w1bb + (size_t)(o_base + col) * 64 + ks * 32 + quad * 8);
#pragma unroll
    for (int nt = 0; nt < 2; ++nt) {
      short8 bf = *(const short8*)(inter_clh + (size_t)(pg0 + nt * 16 + col) * 64 + ks * 32 + quad * 8);
      ag[nt] = __builtin_amdgcn_mfma_f32_16x16x32_bf16(a_g, bf, ag[nt], 0, 0, 0);
      ab[nt] = __builtin_amdgcn_mfma_f32_16x16x32_bf16(a_b, bf, ab[nt], 0, 0, 0);
    }
  }
#pragma unroll
  for (int nt = 0; nt < 2; ++nt) {
    int px = nt * 16 + col;
    ushort pkg[4], pkb[4];
#pragma unroll
    for (int r = 0; r < 4; ++r) {
      float vg = ag[nt][r]; vg = vg >= 0.f ? vg : 0.1f * vg;
      float vb = ab[nt][r]; vb = vb >= 0.f ? vb : 0.1f * vb;
      pkg[r] = f2bf(vg); pkb[r] = f2bf(vb);
    }
    *(uint2*)(&Sg[px * FPX + o_base + quad * 4]) = *(uint2*)pkg;
    *(uint2*)(&Sb[px * FPX + o_base + quad * 4]) = *(uint2*)pkb;
  }
  __syncthreads();   // B1: oml + Sg/Sb visible

  // ---- phase 4: SFT stage B; fold gamma/beta+x -> ev[2][4] ----
  f32x4 gg[2], gb[2];
#pragma unroll
  for (int nt = 0; nt < 2; ++nt) {
    gg[nt] = (f32x4){0.f, 0.f, 0.f, 0.f};
    gb[nt] = (f32x4){0.f, 0.f, 0.f, 0.f};
  }
#pragma unroll
  for (int ks = 0; ks < 2; ++ks) {
    short8 a_g = *(const short8*)(w2gb + (size_t)(o_base + col) * 64 + ks * 32 + quad * 8);
    short8 a_b = *(const short8*)(w2bb + (size_t)(o_base + col) * 64 + ks * 32 + quad * 8);
#pragma unroll
    for (int nt = 0; nt < 2; ++nt) {
      short8 bgf = *(const short8*)(Sg + (nt * 16 + col) * FPX + ks * 32 + quad * 8);
      short8 bbf = *(const short8*)(Sb + (nt * 16 + col) * FPX + ks * 32 + quad * 8);
      gg[nt] = __builtin_amdgcn_mfma_f32_16x16x32_bf16(a_g, bgf, gg[nt], 0, 0, 0);
      gb[nt] = __builtin_amdgcn_mfma_f32_16x16x32_bf16(a_b, bbf, gb[nt], 0, 0, 0);
    }
  }
  float ev[2][4];
#pragma unroll
  for (int nt = 0; nt < 2; ++nt)
#pragma unroll
    for (int r = 0; r < 4; ++r) {
      int o = o_base + quad * 4 + r;
      float xv = x[(size_t)(b * 64 + o) * HW + hw0 + nt * 16 + col];
      ev[nt][r] = xv + xv * gg[nt][r] + gb[nt][r];
    }
  __syncthreads();   // B2: Sg/Sb dead; region becomes coords

  // ---- phase 5: coords once per (pixel, tap) from om_local ----
  for (int i = tid; i < 9 * NPX; i += 256) {
    int k = i >> 5, p = i & 31;
    float dy = oml[k * 33 + p] + b_off[k];
    float dx = oml[(9 + k) * 33 + p] + b_off[9 + k];
    float mz = oml[(18 + k) * 33 + p] + b_off[18 + k];
    float py = (float)(h + (k / 3) - 1) + dy;
    float px = (float)(w0 + p + (k % 3) - 1) + dx;
    float y0f = floorf(py), x0f = floorf(px);
    cy[i] = (int)y0f;
    cx[i] = (int)x0f;
    cwy[i] = py - y0f;
    cwx[i] = px - x0f;
    cm[i] = 1.f / (1.f + __expf(-mz));
  }

  f32x4 acc[2];
  acc[0] = (f32x4){0.f, 0.f, 0.f, 0.f};
  acc[1] = (f32x4){0.f, 0.f, 0.f, 0.f};

  const ushort* bp = x_clh + (size_t)b * HW * 64;
  int p = wave * 8 + rr;

  // ---- phase 6: gather + MFMA, software-pipelined corner bank ----
  // bank: chunk's 3 its x 4 corners (12 short8 = 48 VGPRs) + 9 scalars
  short8 k00[3], k01[3], k10[3], k11[3];
  float kwy[3], kwx[3], km[3];

  __syncthreads();   // B3: coords ready

  // prologue: load chunk 0 (latency exposed, as in round-1)
#pragma unroll
  for (int it = 0; it < 3; ++it) {
    int idx = it * NPX + p;
    int y0 = cy[idx], x0 = cx[idx];
    kwy[it] = cwy[idx]; kwx[it] = cwx[idx]; km[it] = cm[idx];
    bool yok0 = (unsigned)y0 < 128u, yok1 = (unsigned)(y0 + 1) < 128u;
    bool xok0 = (unsigned)x0 < 128u, xok1 = (unsigned)(x0 + 1) < 128u;
    const ushort* r0 = bp + ((size_t)(int)((y0 << 7) + x0)) * 64 + g * 8;
    const ushort* r1 = r0 + (size_t)WW * 64;
    k00[it] = *(const short8*)((yok0 && xok0) ? r0 : zp16);
    k01[it] = *(const short8*)((yok0 && xok1) ? (r0 + 64) : zp16);
    k10[it] = *(const short8*)((yok1 && xok0) ? r1 : zp16);
    k11[it] = *(const short8*)((yok1 && xok1) ? (r1 + 64) : zp16);
  }

#pragma unroll 1
  for (int chunk = 0; chunk < 3; ++chunk) {
    if (chunk) __syncthreads();      // S free (prev MFMA done)
    // bilerp current bank -> S
#pragma unroll
    for (int it = 0; it < 3; ++it) {
      float wy = kwy[it], wx = kwx[it], m = km[it];
      short8 outv;
#pragma unroll
      for (int j = 0; j < 8; ++j) {
        float v00 = bf2f((ushort)k00[it][j]), v01 = bf2f((ushort)k01[it][j]);
        float v10 = bf2f((ushort)k10[it][j]), v11 = bf2f((ushort)k11[it][j]);
        float top = v00 + (v01 - v00) * wx;
        float bot = v10 + (v11 - v10) * wx;
        float val = top + (bot - top) * wy;
        outv[j] = (short)f2bf(val * m);
      }
      *(short8*)(&S[p * SPITCH + it * 64 + g * 8]) = outv;
    }
    // issue NEXT chunk's loads now; latency hides under barrier+MFMA+barrier
    if (chunk < 2) {
#pragma unroll
      for (int it = 0; it < 3; ++it) {
        int idx = ((chunk + 1) * 3 + it) * NPX + p;
        int y0 = cy[idx], x0 = cx[idx];
        kwy[it] = cwy[idx]; kwx[it] = cwx[idx]; km[it] = cm[idx];
        bool yok0 = (unsigned)y0 < 128u, yok1 = (unsigned)(y0 + 1) < 128u;
        bool xok0 = (unsigned)x0 < 128u, xok1 = (unsigned)(x0 + 1) < 128u;
        const ushort* r0 = bp + ((size_t)(int)((y0 << 7) + x0)) * 64 + g * 8;
        const ushort* r1 = r0 + (size_t)WW * 64;
        k00[it] = *(const short8*)((yok0 && xok0) ? r0 : zp16);
        k01[it] = *(const short8*)((yok0 && xok1) ? (r0 + 64) : zp16);
        k10[it] = *(const short8*)((yok1 && xok0) ? r1 : zp16);
        k11[it] = *(const short8*)((yok1 && xok1) ? (r1 + 64) : zp16);
      }
    }
    __syncthreads();                 // S ready
    const ushort* wrow = wdT + (size_t)(o_base + col) * 576 + chunk * 192 + quad * 8;
    const ushort* srow = S + quad * 8;
#pragma unroll
    for (int ks = 0; ks < 6; ++ks) {
      short8 a = *(const short8*)(wrow + ks * 32);
#pragma unroll
      for (int nt = 0; nt < 2; ++nt) {
        short8 bf = *(const short8*)(srow + (nt * 16 + col) * SPITCH + ks * 32);
        acc[nt] = __builtin_amdgcn_mfma_f32_16x16x32_bf16(a, bf, acc[nt], 0, 0, 0);
      }
    }
  }

  // ---- phase 7: epilogue: out = ev + dcn (single pure write) ----
#pragma unroll
  for (int nt = 0; nt < 2; ++nt) {
#pragma unroll
    for (int r = 0; r < 4; ++r) {
      int o = o_base + quad * 4 + r;
      size_t idx = (size_t)(b * 64 + o) * HW + hw0 + nt * 16 + col;
      out[idx] = ev[nt][r] + acc[nt][r];
    }
  }
}

// ---------------------------------------------------------------------------
// Workspace plan (float slots), compacted ~17 MB (round-4/5 verified):
//   x_clh     ushort [0        .. 2097152)
//   inter_clh ushort [2097152  .. 4194304)
//   wfb       ushort [4194304  .. 4212736)
//   wdT       ushort [4212736  .. 4231168)
//   w1gb/w1bb/w2gb/w2bb ushort 4 x 2048 float slots [4231168 .. 4239360)
//   zp        fp32   [4239360  .. 4239424)
// ---------------------------------------------------------------------------
extern "C" void kernel_launch(void* const* d_in, const int* in_sizes, int n_in,
                              void* d_out, int out_size, void* d_ws, size_t ws_size,
                              hipStream_t stream) {
  const float* x     = (const float*)d_in[0];
  const float* inter = (const float*)d_in[1];
  const float* w_off = (const float*)d_in[2];
  const float* b_off = (const float*)d_in[3];
  const float* w_dcn = (const float*)d_in[4];
  const float* wg1   = (const float*)d_in[5];
  const float* wg2   = (const float*)d_in[6];
  const float* wb1   = (const float*)d_in[7];
  const float* wb2   = (const float*)d_in[8];
  float* out = (float*)d_out;

  float* ws        = (float*)d_ws;
  ushort* x_clh    = (ushort*)ws;
  ushort* inter_clh= (ushort*)(ws + 2097152);
  ushort* wfb      = (ushort*)(ws + 4194304);
  ushort* wdT      = (ushort*)(ws + 4212736);
  ushort* w1gb     = (ushort*)(ws + 4231168);
  ushort* w1bb     = (ushort*)(ws + 4233216);
  ushort* w2gb     = (ushort*)(ws + 4235264);
  ushort* w2bb     = (ushort*)(ws + 4237312);
  float* zp        = ws + 4239360;

  // Prep: channels-last bf16 inputs + all packed weights + zero page.
  k_prep<<<1376, 256, 0, stream>>>(x, inter, w_off, w_dcn, wg1, wb1, wg2, wb2,
                                   x_clh, inter_clh, wfb, wdT,
                                   w1gb, w1bb, w2gb, w2bb, zp);

  // Fully fused conv + SFT + DCN (round-1 structure + pipelined phase 6).
  k_omega<<<2048, 256, 0, stream>>>(x, x_clh, inter_clh, b_off, wfb, wdT,
                                    w1gb, w1bb, w2gb, w2bb,
                                    (const ushort*)zp, out);
}

// Round 7
// 169.206 us; speedup vs baseline: 1.3467x; 1.0295x over previous
//
#include <hip/hip_runtime.h>
#include <hip/hip_bf16.h>
#include <math.h>

#define BB 4
#define CC 64
#define HH 128
#define WW 128
#define HW (HH*WW)          // 16384
#define NPIX (BB*HW)        // 65536

typedef __attribute__((ext_vector_type(8))) short short8;   // 8 bf16
typedef __attribute__((ext_vector_type(4))) float f32x4;

__device__ __forceinline__ float bf2f(ushort u) {
  union { unsigned u; float f; } v; v.u = ((unsigned)u) << 16; return v.f;
}
__device__ __forceinline__ ushort f2bf(float f) {
  __hip_bfloat16 h = __float2bfloat16(f); return *(ushort*)&h;
}

// ---------------------------------------------------------------------------
// Prep (round-1 verified): NCHW fp32 -> channels-last bf16 + weights.
// ---------------------------------------------------------------------------
__global__ __launch_bounds__(256) void k_prep(
    const float* __restrict__ x, const float* __restrict__ inter,
    const float* __restrict__ w_off, const float* __restrict__ w_dcn,
    const float* __restrict__ wg1, const float* __restrict__ wb1,
    const float* __restrict__ wg2, const float* __restrict__ wb2,
    ushort* __restrict__ x_clh, ushort* __restrict__ inter_clh,
    ushort* __restrict__ wfb, ushort* __restrict__ wdT,
    ushort* __restrict__ w1gb, ushort* __restrict__ w1bb,
    ushort* __restrict__ w2gb, ushort* __restrict__ w2bb,
    float* __restrict__ zp) {
  __shared__ __align__(16) float tile[64 * 128];   // 32 KiB, xor-swizzled
  int blk = blockIdx.x;
  int tid = threadIdx.x;
  if (blk < 1024) {
    int sel = blk >> 9;
    int bh = blk & 511;
    int b = bh >> 7, h = bh & 127;
    const float* src = sel ? inter : x;
    ushort* dst = sel ? inter_clh : x_clh;
    const float* sp = src + (size_t)(b * 64) * HW + h * WW;
#pragma unroll
    for (int it = 0; it < 8; ++it) {
      int idx = it * 256 + tid;
      int c = idx >> 5, wq = idx & 31;
      float4 v = *(const float4*)(sp + (size_t)c * HW + wq * 4);
      int s = (c >> 3) & 7;
      *(float4*)(&tile[c * 128 + ((wq ^ s) << 2)]) = v;
    }
    __syncthreads();
    ushort* dp = dst + ((size_t)b * HW + h * WW) * 64;
#pragma unroll
    for (int it = 0; it < 4; ++it) {
      int idx = it * 256 + tid;
      int w = idx >> 3, c8 = idx & 7;
      short8 outv;
#pragma unroll
      for (int j = 0; j < 8; ++j) {
        int c = c8 * 8 + j;
        int sl = (w >> 2) ^ c8;
        float f = tile[c * 128 + (sl << 2) + (w & 3)];
        outv[j] = (short)f2bf(f);
      }
      *(short8*)(dp + (size_t)w * 64 + c8 * 8) = outv;
    }
  } else if (blk < 1168) {
    int i = (blk - 1024) * 256 + tid;
    if (i < 64) zp[i] = 0.f;
    if (i < 9 * 32 * 128) {
      int tap = i >> 12, rem = i & 4095, m = rem >> 7, c = rem & 127;
      float v = (m < 27) ? w_off[(size_t)(m * 128 + c) * 9 + tap] : 0.f;
      wfb[i] = f2bf(v);
    }
  } else if (blk < 1312) {
    int i = (blk - 1168) * 256 + tid;
    if (i < 64 * 64 * 9) {
      int o = i / 576, rem = i % 576, k = rem >> 6, c = rem & 63;
      wdT[i] = f2bf(w_dcn[(o * 64 + c) * 9 + k]);
    }
  } else {
    int i = (blk - 1312) * 256 + tid;   // 0..16383
    int m = i >> 12, j = i & 4095;
    const float* src = (m == 0) ? wg1 : (m == 1) ? wb1 : (m == 2) ? wg2 : wb2;
    ushort* dst = (m == 0) ? w1gb : (m == 1) ? w1bb : (m == 2) ? w2gb : w2bb;
    dst[j] = f2bf(src[j]);
  }
}

// ---------------------------------------------------------------------------
// OMEGA v7 = byte-exact round-1 kernel (session best, 83 us) + ONE change:
//   XCD-chunked block swizzle. wid = (bid&7)*256 + (bid>>3) (bijective,
//   2048%8==0). HW dispatch round-robins bid across the 8 XCDs, so XCD k
//   receives wids [k*256,(k+1)*256) = HALF OF ONE batch image, contiguous:
//   x_clh slab ~1 MB + inter_clh ~1 MB + x fp32 ~2 MB fit its 4 MB L2.
//   The 9-tap gather (offsets ~ +-1 px) re-reads x_clh 9x -> now L2 hits
//   (~200 cy) instead of L3 (~600-900 cy). Targets the barrier-drained
//   scattered-load exposures that dominate the per-block critical path.
// Round-6's corner-bank pipeline REVERTED (barrier drains vmcnt -> useless,
// and it cost 16 VGPR + occupancy). No launch_bounds clamp (spill tripwire).
// LDS alias map (bytes in BIGB, 29376 B):
//   [0,29376)      phase 1-2: conv halo (204 rows x 72 shorts)
//   [0,12800)      phase 6:   S gather buffer (32 px x 200 shorts)
//   [12800,22016)  phase 3-4: Sg/Sb (2 x 32 x 72 shorts)
//   [12800,18560)  phase 5-6: coords (5 x 288 x 4 B)
//   [22016,25712)  phase 3-6: om_local (27 x 33 f32, written after halo dies)
// ---------------------------------------------------------------------------
#define CPITCH 72    // shorts per (srcrow, px) channel row in conv halo
#define SPITCH 200   // shorts per pixel row in gather buffer S
#define NPX 32       // pixels per block
#define FPX 72       // shorts per px row in Sg/Sb

__global__ __launch_bounds__(256) void k_omega(
    const float* __restrict__ x, const ushort* __restrict__ x_clh,
    const ushort* __restrict__ inter_clh,
    const float* __restrict__ b_off, const ushort* __restrict__ wfb,
    const ushort* __restrict__ wdT,
    const ushort* __restrict__ w1gb, const ushort* __restrict__ w1bb,
    const ushort* __restrict__ w2gb, const ushort* __restrict__ w2bb,
    const ushort* __restrict__ zp16, float* __restrict__ out) {
  __shared__ __align__(16) ushort BIGB[6 * 34 * CPITCH];   // 29376 B total LDS
  ushort* S  = BIGB;                      // 32*200 shorts = 12800 B (phases 1,6)
  ushort* Sg = BIGB + 6400;               // 32*72 shorts (phases 3-4)
  ushort* Sb = Sg + NPX * FPX;            // ends at short 11008 = byte 22016
  int*   cy  = (int*)(BIGB + 6400);       // coords (phases 5-6): 288 each
  int*   cx  = cy + 288;
  float* cwy = (float*)(cx + 288);
  float* cwx = cwy + 288;
  float* cm  = cwx + 288;                 // 5760 B total, ends byte 18560
  float* oml = (float*)(BIGB + 11008);    // om_local 27x33 f32 @ byte 22016

  int tid = threadIdx.x;
  int wave = tid >> 6, lane = tid & 63;
  int quad = lane >> 4, col = lane & 15;
  int rr = lane >> 3, g = lane & 7;
  // XCD-chunked swizzle: the ONLY change vs round-1.
  int bid = blockIdx.x;
  int wid = (bid & 7) * 256 + (bid >> 3);
  int pg0 = wid * NPX;
  int b = pg0 >> 14, hw0 = pg0 & 16383;
  int h = hw0 >> 7, w0 = hw0 & 127;
  int pt = wave >> 1, mt = wave & 1;
  int o_base = __builtin_amdgcn_readfirstlane(wave * 16);

  // ---- phase 1: conv halo staging ----
  {
    int ch = (tid & 7) * 8;
    unsigned bbase = (unsigned)b * HW;
#pragma unroll
    for (int it = 0; it < 7; ++it) {
      int e = it * 32 + (tid >> 3);
      if (e < 204) {
        int srcrow = e / 34, pxl = e % 34;
        int src = srcrow / 3, row = srcrow % 3;
        int hs = h + row - 1;
        int ps = w0 + pxl - 1;
        bool ok = ((unsigned)hs < 128u) && ((unsigned)ps < 128u);
        int hc = hs < 0 ? 0 : (hs > 127 ? 127 : hs);
        int pc = ps < 0 ? 0 : (ps > 127 ? 127 : ps);
        const ushort* sb = src ? inter_clh : x_clh;
        short8 v = *(const short8*)(sb + ((size_t)(bbase + (hc << 7) + pc)) * 64 + ch);
        short8 z = {0, 0, 0, 0, 0, 0, 0, 0};
        if (!ok) v = z;
        *(short8*)(&BIGB[e * CPITCH + ch]) = v;
      }
    }
  }
  __syncthreads();

  // ---- phase 2: conv MFMAs -> registers (oml store deferred past barrier) ----
  f32x4 accx = {0.f, 0.f, 0.f, 0.f}, acci = {0.f, 0.f, 0.f, 0.f};
  {
    const ushort* wb0 = wfb + (size_t)(mt * 16 + col) * 128 + quad * 8;
    int pxb = pt * 16 + col;
#pragma unroll
    for (int ky = 0; ky < 3; ++ky) {
#pragma unroll
      for (int kx = 0; kx < 3; ++kx) {
        int tap = ky * 3 + kx;
        const ushort* wt = wb0 + (size_t)tap * 4096;
#pragma unroll
        for (int ks = 0; ks < 2; ++ks) {
          short8 a0 = *(const short8*)(wt + ks * 32);
          short8 b0 = *(const short8*)(&BIGB[(ky * 34 + pxb + kx) * CPITCH + ks * 32 + quad * 8]);
          accx = __builtin_amdgcn_mfma_f32_16x16x32_bf16(a0, b0, accx, 0, 0, 0);
          short8 a1 = *(const short8*)(wt + 64 + ks * 32);
          short8 b1 = *(const short8*)(&BIGB[((3 + ky) * 34 + pxb + kx) * CPITCH + ks * 32 + quad * 8]);
          acci = __builtin_amdgcn_mfma_f32_16x16x32_bf16(a1, b1, acci, 0, 0, 0);
        }
      }
    }
  }
  __syncthreads();   // all waves done READING halo; BIGB free for aliases

  // oml store into BIGB tail (disjoint from Sg/Sb written in phase 3).
#pragma unroll
  for (int r = 0; r < 4; ++r) {
    int o = mt * 16 + quad * 4 + r;
    if (o < 27) oml[o * 33 + pt * 16 + col] = accx[r] + acci[r];
  }

  // ---- phase 3: SFT stage A -> Sg/Sb ----
  f32x4 ag[2], ab[2];
#pragma unroll
  for (int nt = 0; nt < 2; ++nt) {
    ag[nt] = (f32x4){0.f, 0.f, 0.f, 0.f};
    ab[nt] = (f32x4){0.f, 0.f, 0.f, 0.f};
  }
#pragma unroll
  for (int ks = 0; ks < 2; ++ks) {
    short8 a_g = *(const short8*)(w1gb + (size_t)(o_base + col) * 64 + ks * 32 + quad * 8);
    short8 a_b = *(const short8*)(w1bb + (size_t)(o_base + col) * 64 + ks * 32 + quad * 8);
#pragma unroll
    for (int nt = 0; nt < 2; ++nt) {
      short8 bf = *(const short8*)(inter_clh + (size_t)(pg0 + nt * 16 + col) * 64 + ks * 32 + quad * 8);
      ag[nt] = __builtin_amdgcn_mfma_f32_16x16x32_bf16(a_g, bf, ag[nt], 0, 0, 0);
      ab[nt] = __builtin_amdgcn_mfma_f32_16x16x32_bf16(a_b, bf, ab[nt], 0, 0, 0);
    }
  }
#pragma unroll
  for (int nt = 0; nt < 2; ++nt) {
    int px = nt * 16 + col;
    ushort pkg[4], pkb[4];
#pragma unroll
    for (int r = 0; r < 4; ++r) {
      float vg = ag[nt][r]; vg = vg >= 0.f ? vg : 0.1f * vg;
      float vb = ab[nt][r]; vb = vb >= 0.f ? vb : 0.1f * vb;
      pkg[r] = f2bf(vg); pkb[r] = f2bf(vb);
    }
    *(uint2*)(&Sg[px * FPX + o_base + quad * 4]) = *(uint2*)pkg;
    *(uint2*)(&Sb[px * FPX + o_base + quad * 4]) = *(uint2*)pkb;
  }
  __syncthreads();

  // ---- phase 4: SFT stage B -> gamma/beta in registers ----
  f32x4 gg[2], gb[2];
#pragma unroll
  for (int nt = 0; nt < 2; ++nt) {
    gg[nt] = (f32x4){0.f, 0.f, 0.f, 0.f};
    gb[nt] = (f32x4){0.f, 0.f, 0.f, 0.f};
  }
#pragma unroll
  for (int ks = 0; ks < 2; ++ks) {
    short8 a_g = *(const short8*)(w2gb + (size_t)(o_base + col) * 64 + ks * 32 + quad * 8);
    short8 a_b = *(const short8*)(w2bb + (size_t)(o_base + col) * 64 + ks * 32 + quad * 8);
#pragma unroll
    for (int nt = 0; nt < 2; ++nt) {
      short8 bgf = *(const short8*)(Sg + (nt * 16 + col) * FPX + ks * 32 + quad * 8);
      short8 bbf = *(const short8*)(Sb + (nt * 16 + col) * FPX + ks * 32 + quad * 8);
      gg[nt] = __builtin_amdgcn_mfma_f32_16x16x32_bf16(a_g, bgf, gg[nt], 0, 0, 0);
      gb[nt] = __builtin_amdgcn_mfma_f32_16x16x32_bf16(a_b, bbf, gb[nt], 0, 0, 0);
    }
  }
  // Prefetch epilogue x values (independent of everything below).
  float xv[2][4];
#pragma unroll
  for (int nt = 0; nt < 2; ++nt)
#pragma unroll
    for (int r = 0; r < 4; ++r) {
      int o = o_base + quad * 4 + r;
      xv[nt][r] = x[(size_t)(b * 64 + o) * HW + hw0 + nt * 16 + col];
    }
  __syncthreads();   // Sg/Sb dead; region becomes coords

  // ---- phase 5: coords once per (pixel, tap) from om_local ----
  for (int i = tid; i < 9 * NPX; i += 256) {
    int k = i >> 5, p = i & 31;
    float dy = oml[k * 33 + p] + b_off[k];
    float dx = oml[(9 + k) * 33 + p] + b_off[9 + k];
    float mz = oml[(18 + k) * 33 + p] + b_off[18 + k];
    float py = (float)(h + (k / 3) - 1) + dy;
    float px = (float)(w0 + p + (k % 3) - 1) + dx;
    float y0f = floorf(py), x0f = floorf(px);
    cy[i] = (int)y0f;
    cx[i] = (int)x0f;
    cwy[i] = py - y0f;
    cwx[i] = px - x0f;
    cm[i] = 1.f / (1.f + __expf(-mz));
  }

  f32x4 acc[2];
  acc[0] = (f32x4){0.f, 0.f, 0.f, 0.f};
  acc[1] = (f32x4){0.f, 0.f, 0.f, 0.f};

  const ushort* bp = x_clh + (size_t)b * HW * 64;

  // ---- phase 6: gather + MFMA chunks ----
  for (int chunk = 0; chunk < 3; ++chunk) {
    __syncthreads();   // chunk 0: coords ready; later: S free for reuse
#pragma unroll
    for (int it = 0; it < 3; ++it) {
      int p = wave * 8 + rr;
      int idx = (chunk * 3 + it) * NPX + p;
      int y0 = cy[idx], x0 = cx[idx];
      float wy = cwy[idx], wx = cwx[idx], m = cm[idx];
      bool yok0 = (unsigned)y0 < 128u, yok1 = (unsigned)(y0 + 1) < 128u;
      bool xok0 = (unsigned)x0 < 128u, xok1 = (unsigned)(x0 + 1) < 128u;
      const ushort* r0 = bp + ((size_t)(int)((y0 << 7) + x0)) * 64 + g * 8;
      const ushort* r1 = r0 + (size_t)WW * 64;
      short8 s00 = *(const short8*)((yok0 && xok0) ? r0 : zp16);
      short8 s01 = *(const short8*)((yok0 && xok1) ? (r0 + 64) : zp16);
      short8 s10 = *(const short8*)((yok1 && xok0) ? r1 : zp16);
      short8 s11 = *(const short8*)((yok1 && xok1) ? (r1 + 64) : zp16);
      short8 outv;
#pragma unroll
      for (int j = 0; j < 8; ++j) {
        float v00 = bf2f((ushort)s00[j]), v01 = bf2f((ushort)s01[j]);
        float v10 = bf2f((ushort)s10[j]), v11 = bf2f((ushort)s11[j]);
        float top = v00 + (v01 - v00) * wx;
        float bot = v10 + (v11 - v10) * wx;
        float val = top + (bot - top) * wy;
        outv[j] = (short)f2bf(val * m);
      }
      *(short8*)(&S[p * SPITCH + it * 64 + g * 8]) = outv;
    }
    __syncthreads();
    const ushort* wrow = wdT + (size_t)(o_base + col) * 576 + chunk * 192 + quad * 8;
    const ushort* srow = S + quad * 8;
#pragma unroll
    for (int ks = 0; ks < 6; ++ks) {
      short8 a = *(const short8*)(wrow + ks * 32);
#pragma unroll
      for (int nt = 0; nt < 2; ++nt) {
        short8 bf = *(const short8*)(srow + (nt * 16 + col) * SPITCH + ks * 32);
        acc[nt] = __builtin_amdgcn_mfma_f32_16x16x32_bf16(a, bf, acc[nt], 0, 0, 0);
      }
    }
  }

  // ---- phase 7: epilogue: out = x + x*gamma + beta + dcn (single write) ----
#pragma unroll
  for (int nt = 0; nt < 2; ++nt) {
#pragma unroll
    for (int r = 0; r < 4; ++r) {
      int o = o_base + quad * 4 + r;
      size_t idx = (size_t)(b * 64 + o) * HW + hw0 + nt * 16 + col;
      out[idx] = xv[nt][r] + xv[nt][r] * gg[nt][r] + gb[nt][r] + acc[nt][r];
    }
  }
}

// ---------------------------------------------------------------------------
// Workspace plan (float slots), compacted ~17 MB (r4-verified):
//   x_clh     ushort [0        .. 2097152)
//   inter_clh ushort [2097152  .. 4194304)
//   wfb       ushort [4194304  .. 4212736)
//   wdT       ushort [4212736  .. 4231168)
//   w1gb/w1bb/w2gb/w2bb ushort 4 x 2048 float slots [4231168 .. 4239360)
//   zp        fp32   [4239360  .. 4239424)
// ---------------------------------------------------------------------------
extern "C" void kernel_launch(void* const* d_in, const int* in_sizes, int n_in,
                              void* d_out, int out_size, void* d_ws, size_t ws_size,
                              hipStream_t stream) {
  const float* x     = (const float*)d_in[0];
  const float* inter = (const float*)d_in[1];
  const float* w_off = (const float*)d_in[2];
  const float* b_off = (const float*)d_in[3];
  const float* w_dcn = (const float*)d_in[4];
  const float* wg1   = (const float*)d_in[5];
  const float* wg2   = (const float*)d_in[6];
  const float* wb1   = (const float*)d_in[7];
  const float* wb2   = (const float*)d_in[8];
  float* out = (float*)d_out;

  float* ws        = (float*)d_ws;
  ushort* x_clh    = (ushort*)ws;
  ushort* inter_clh= (ushort*)(ws + 2097152);
  ushort* wfb      = (ushort*)(ws + 4194304);
  ushort* wdT      = (ushort*)(ws + 4212736);
  ushort* w1gb     = (ushort*)(ws + 4231168);
  ushort* w1bb     = (ushort*)(ws + 4233216);
  ushort* w2gb     = (ushort*)(ws + 4235264);
  ushort* w2bb     = (ushort*)(ws + 4237312);
  float* zp        = ws + 4239360;

  // Prep: channels-last bf16 inputs + all packed weights + zero page.
  k_prep<<<1376, 256, 0, stream>>>(x, inter, w_off, w_dcn, wg1, wb1, wg2, wb2,
                                   x_clh, inter_clh, wfb, wdT,
                                   w1gb, w1bb, w2gb, w2bb, zp);

  // Fully fused conv + SFT + DCN (round-1 structure + XCD-chunked swizzle).
  k_omega<<<2048, 256, 0, stream>>>(x, x_clh, inter_clh, b_off, wfb, wdT,
                                    w1gb, w1bb, w2gb, w2bb,
                                    (const ushort*)zp, out);
}